// Round 6
// baseline (361.782 us; speedup 1.0000x reference)
//
#include <hip/hip_runtime.h>
#include <hip/hip_bf16.h>

// ModulatedConv2d: B=8, Cin=Cout=512, K=3, H=W=64, pad=1, groups=B.
// bf16 MFMA implicit GEMM per batch: C[512,4096] = Wmod[512,4608] x Im2col.
// R6: AITER-style K-loop — 3 LDS stages, 2-deep GLDS prefetch, raw s_barrier
// with s_waitcnt vmcnt(6) (never 0 in steady state): the wait covers only the
// stage issued two compute-phases ago, so global->LDS flight is fully hidden.
// Block tile 256x128 (4 waves of 128x64, 16x16x32 MFMA), BK=32, 144 stages.

#define CIN   512
#define COUT  512
#define KDIM  4608        // 9 * 512
#define HWPIX 4096

typedef __attribute__((ext_vector_type(8))) __bf16 bf16x8;
typedef __attribute__((ext_vector_type(4))) float  f32x4;

__device__ __forceinline__ unsigned short f2bf(float f){
  union { float f; unsigned int u; } v; v.f = f;
  unsigned int u = v.u;
  u += 0x7fffu + ((u >> 16) & 1u);     // round-to-nearest-even
  return (unsigned short)(u >> 16);
}

#define GLDS16(g, l) __builtin_amdgcn_global_load_lds(                      \
    (const __attribute__((address_space(1))) unsigned int*)(g),             \
    (__attribute__((address_space(3))) unsigned int*)(l), 16, 0, 0)

// ---------------- styles: s[b][c] = dot(w[b], affine_w[c]) + ab[c] + 1 ----
__global__ void style_k(const float* __restrict__ w, const float* __restrict__ aw,
                        const float* __restrict__ ab, float* __restrict__ styles){
  int wid = threadIdx.x >> 6, lane = threadIdx.x & 63;
  int gid = blockIdx.x * 4 + wid;           // 0..4095 = b*512 + c
  int b = gid >> 9, c = gid & 511;
  const float* wb = w + b * 512;
  const float* ar = aw + c * 512;
  float sum = 0.f;
  for (int j = lane; j < 512; j += 64) sum += wb[j] * ar[j];
  for (int off = 32; off; off >>= 1) sum += __shfl_down(sum, off, 64);
  if (lane == 0) styles[gid] = sum + ab[c] + 1.0f;
}

// ------------- modulate + demodulate -> bf16 wmod[b][o][tap*512+cin] ------
__global__ void modw_k(const float* __restrict__ weight, const float* __restrict__ styles,
                       unsigned short* __restrict__ wmod){
  int o = blockIdx.x, b = blockIdx.y;
  int t = threadIdx.x;
  const float* wrow = weight + (size_t)o * KDIM;   // weight[0][o][i][ky][kx]
  const float* st   = styles + b * 512;
  __shared__ unsigned short sw[9 * 520];           // tap stride 520 (pad vs 512)
  __shared__ float red[4];
  float vals[18];
  float part = 0.f;
#pragma unroll
  for (int it = 0; it < 18; ++it){
    int idx = it * 256 + t;             // coalesced over threads
    int i = idx / 9;
    float v = wrow[idx] * st[i];
    vals[it] = v;
    part += v * v;
  }
  int wid = t >> 6, lane = t & 63;
  for (int off = 32; off; off >>= 1) part += __shfl_down(part, off, 64);
  if (lane == 0) red[wid] = part;
  __syncthreads();
  float d = rsqrtf(red[0] + red[1] + red[2] + red[3] + 1e-8f);
#pragma unroll
  for (int it = 0; it < 18; ++it){
    int idx = it * 256 + t;
    int i = idx / 9;
    int tap = idx - i * 9;
    sw[tap * 520 + i] = f2bf(vals[it] * d);
  }
  __syncthreads();
  unsigned int* orow32 = (unsigned int*)(wmod + ((size_t)(b * 512 + o)) * KDIM);
#pragma unroll
  for (int it = 0; it < 9; ++it){       // 2304 dwords, fully coalesced
    int u = it * 256 + t;
    int e = u * 2;
    int tap2 = e >> 9, i2 = e & 511;
    orow32[u] = *(const unsigned int*)&sw[tap2 * 520 + i2];
  }
}

// ----- transpose+pad: x[b][c][h][w] fp32 -> xpad[b][h+1][w+1][c] bf16 -----
__global__ void xpose_k(const float* __restrict__ x, unsigned short* __restrict__ xpad){
  int h = blockIdx.x, cg = blockIdx.y, b = blockIdx.z;
  int c0 = cg * 64;
  __shared__ unsigned short lds[64][66];   // [w][c]: writes 2-way (free), reads clean
  int t = threadIdx.x;
  const float* xb = x + (((size_t)(b * 512 + c0)) * 64 + h) * 64;
#pragma unroll
  for (int it = 0; it < 16; ++it){
    int idx = it * 256 + t;
    int cl = idx >> 6, wl = idx & 63;     // cl wave-uniform, wl = lane
    lds[wl][cl] = f2bf(xb[(size_t)cl * 4096 + wl]);
  }
  if (t < 64){
    int which = t >> 5;                   // 0: w=0, 1: w=65
    int ch2 = (t & 31) * 2;
    int wl = which ? 65 : 0;
    *(unsigned int*)&xpad[(((size_t)b * 66 + h + 1) * 66 + wl) * 512 + c0 + ch2] = 0u;
  }
  if (h == 0 || h == 63){                 // rows 0 / 65, all 66 w
    int row = (h == 0) ? 0 : 65;
    for (int u = t; u < 66 * 32; u += 256){
      int wl = u >> 5, ch2 = (u & 31) * 2;
      *(unsigned int*)&xpad[(((size_t)b * 66 + row) * 66 + wl) * 512 + c0 + ch2] = 0u;
    }
  }
  __syncthreads();
#pragma unroll
  for (int it = 0; it < 2; ++it){
    int idx = it * 256 + t;
    int wl = idx >> 3, ch = idx & 7;
    unsigned int u0 = *(const unsigned int*)&lds[wl][ch * 8 + 0];
    unsigned int u1 = *(const unsigned int*)&lds[wl][ch * 8 + 2];
    unsigned int u2 = *(const unsigned int*)&lds[wl][ch * 8 + 4];
    unsigned int u3 = *(const unsigned int*)&lds[wl][ch * 8 + 6];
    int off = ((b * 66 + h + 1) * 66 + (wl + 1)) * 512 + c0 + ch * 8;
    *(uint4*)&xpad[off] = make_uint4(u0, u1, u2, u3);
  }
}

// --------------------------- main conv GEMM ------------------------------
// grid 512 (b==XCD swizzle); 256x128 block tile, 4 waves of 128x64 (8x4 frags);
// BK=32, 144 stages, 3 LDS stage buffers, 2-deep prefetch, raw barriers.
#define WAIT6 "s_waitcnt vmcnt(6) lgkmcnt(0)"
#define WAIT0 "s_waitcnt vmcnt(0) lgkmcnt(0)"

__global__ __launch_bounds__(256, 2) void conv_gemm(
    const unsigned short* __restrict__ wmod, const unsigned short* __restrict__ xpad,
    const float* __restrict__ noise, const float* __restrict__ bias,
    float* __restrict__ out){
  __shared__ unsigned short As[3][256 * 32];   // [stage][m][k32]  16KB each
  __shared__ unsigned short Bs[3][128 * 32];   // [stage][n][k32]   8KB each
  // decode: per XCD one batch (b = xcd), both m-tiles, all 32 n-tiles.
  int g = blockIdx.x;
  int xcd = g & 7, sl = g >> 3;                // sl 0..63
  int b = xcd, mt = sl >> 5, nt = sl & 31;
  int m0 = mt * 256, n0 = nt * 128;
  int h0 = nt * 2;                             // 2 image rows per n-tile
  int tid = threadIdx.x, wid = tid >> 6, lane = tid & 63;
  int wm = wid >> 1, wn = wid & 1;             // wave tile: rows wm*128, cols wn*64
  int lr = lane >> 2;                          // row within 16-row staging group
  int lc = lane & 3;                           // 16B chunk within 64B row

  const unsigned short* wbase = wmod + ((size_t)(b * 512 + m0)) * KDIM;
  int aoffG[4];
#pragma unroll
  for (int i = 0; i < 4; ++i)
    aoffG[i] = ((wid * 64 + i * 16 + lr)) * KDIM + lc * 8;   // A rows wid*64..+63

  const unsigned short* xb = xpad + (size_t)b * 66 * 66 * 512;
  int boffG[2];
#pragma unroll
  for (int i = 0; i < 2; ++i){
    int p = wid * 32 + i * 16 + lr;                          // B rows wid*32..+31
    boffG[i] = ((h0 + (p >> 6) + 1) * 66 + ((p & 63) + 1)) * 512 + lc * 8;
  }
  int albase[4], blbase[2];
#pragma unroll
  for (int i = 0; i < 4; ++i) albase[i] = (wid * 64 + i * 16) * 32;  // wave-uniform
#pragma unroll
  for (int i = 0; i < 2; ++i) blbase[i] = (wid * 32 + i * 16) * 32;

  int fm = lane & 15;
  int k8 = (lane >> 4) * 8;
  int apo[8], bpo[4];
#pragma unroll
  for (int i = 0; i < 8; ++i) apo[i] = (wm * 128 + i * 16 + fm) * 32 + k8;
#pragma unroll
  for (int j = 0; j < 4; ++j) bpo[j] = (wn * 64 + j * 16 + fm) * 32 + k8;

  f32x4 acc[8][4];
#pragma unroll
  for (int i = 0; i < 8; ++i)
#pragma unroll
    for (int j = 0; j < 4; ++j) acc[i][j] = (f32x4){0.f, 0.f, 0.f, 0.f};

  // per-stage staging: 6 GLDS/wave. tap = ks>>4 (32 | 512), c0 = (ks&15)*32.
#define ISSUE_STAGE(ks2, st) {                                              \
    int tap_ = (ks2) >> 4;                                                  \
    int c0_  = ((ks2) & 15) << 5;                                           \
    int k0_  = (tap_ << 9) + c0_;                                           \
    int dy3_ = tap_ / 3;                                                    \
    int bsh_ = (((dy3_ - 1) * 66 + (tap_ - dy3_ * 3 - 1)) << 9) + c0_;      \
    _Pragma("unroll")                                                       \
    for (int i_ = 0; i_ < 4; ++i_)                                          \
      GLDS16(wbase + aoffG[i_] + k0_, &As[st][albase[i_]]);                 \
    _Pragma("unroll")                                                       \
    for (int i_ = 0; i_ < 2; ++i_)                                          \
      GLDS16(xb + boffG[i_] + bsh_, &Bs[st][blbase[i_]]);                   \
  }

#define COMPUTE_STAGE(st) {                                                 \
    bf16x8 af[8], bfr[4];                                                   \
    _Pragma("unroll")                                                       \
    for (int i_ = 0; i_ < 8; ++i_) af[i_]  = *(const bf16x8*)&As[st][apo[i_]]; \
    _Pragma("unroll")                                                       \
    for (int j_ = 0; j_ < 4; ++j_) bfr[j_] = *(const bf16x8*)&Bs[st][bpo[j_]]; \
    _Pragma("unroll")                                                       \
    for (int i_ = 0; i_ < 8; ++i_)                                          \
      _Pragma("unroll")                                                     \
      for (int j_ = 0; j_ < 4; ++j_)                                        \
        acc[i_][j_] = __builtin_amdgcn_mfma_f32_16x16x32_bf16(af[i_], bfr[j_], acc[i_][j_], 0, 0, 0); \
  }

  // BODY(ks): wait for L(ks) (2 stages old), barrier, prefetch L(ks+2), compute.
#define BODY(ks, cst, ist, WAITSTR, DOISSUE) {                              \
    asm volatile(WAITSTR "\n\ts_barrier" ::: "memory");                     \
    if (DOISSUE) ISSUE_STAGE((ks) + 2, ist);                                \
    COMPUTE_STAGE(cst);                                                     \
  }

  ISSUE_STAGE(0, 0);
  ISSUE_STAGE(1, 1);
  for (int kb = 0; kb < 141; kb += 3){
    BODY(kb + 0, 0, 2, WAIT6, true);
    BODY(kb + 1, 1, 0, WAIT6, true);
    BODY(kb + 2, 2, 1, WAIT6, true);
  }
  BODY(141, 0, 2, WAIT6, true);    // issues L(143)
  BODY(142, 1, 0, WAIT6, false);   // outstanding L(142)+L(143)=12 -> drains L(142)
  BODY(143, 2, 1, WAIT0, false);   // drain all

  // epilogue: + noise + bias, leaky relu 0.2. C/D map: row=(lane>>4)*4+reg, col=lane&15
  int quad = lane >> 4;
#pragma unroll
  for (int i = 0; i < 8; ++i){
    int o_base = m0 + wm * 128 + i * 16 + quad * 4;
#pragma unroll
    for (int j = 0; j < 4; ++j){
      int n = n0 + wn * 64 + j * 16 + fm;
#pragma unroll
      for (int r = 0; r < 4; ++r){
        int o = o_base + r;
        size_t idx = ((size_t)(b * 512 + o)) * HWPIX + n;
        float v = acc[i][j][r] + noise[idx] + bias[o];
        out[idx] = (v >= 0.f) ? v : 0.2f * v;
      }
    }
  }
}

extern "C" void kernel_launch(void* const* d_in, const int* in_sizes, int n_in,
                              void* d_out, int out_size, void* d_ws, size_t ws_size,
                              hipStream_t stream) {
  const float* x        = (const float*)d_in[0];
  const float* w        = (const float*)d_in[1];
  const float* noise    = (const float*)d_in[2];
  const float* weight   = (const float*)d_in[3];
  const float* affine_w = (const float*)d_in[4];
  const float* affine_b = (const float*)d_in[5];
  const float* bias     = (const float*)d_in[6];
  float* out = (float*)d_out;

  // workspace: styles 16KB | wmod 37,748,736B | xpad 35,684,352B  (~73.5 MB)
  float* styles = (float*)d_ws;
  unsigned short* wmod = (unsigned short*)((char*)d_ws + 16384);
  unsigned short* xpad = (unsigned short*)((char*)d_ws + 16384 + 37748736ull);

  style_k<<<dim3(1024), 256, 0, stream>>>(w, affine_w, affine_b, styles);
  modw_k <<<dim3(512, 8), 256, 0, stream>>>(weight, styles, wmod);
  xpose_k<<<dim3(64, 8, 8), 256, 0, stream>>>(x, xpad);
  conv_gemm<<<dim3(512), 256, 0, stream>>>(wmod, xpad, noise, bias, out);
}

// Round 7
// 335.343 us; speedup vs baseline: 1.0788x; 1.0788x over previous
//
#include <hip/hip_runtime.h>
#include <hip/hip_bf16.h>

// ModulatedConv2d: B=8, Cin=Cout=512, K=3, H=W=64, pad=1, groups=B.
// bf16 MFMA implicit GEMM per batch: C[512,4096] = Wmod[512,4608] x Im2col.
// R5 structure (best): 256x128 block tile, 4 waves of 128x64, BK=64, 2-barrier
// K-loop, 16x16x32 MFMA, grid 512 (b==XCD swizzle).
// R7: XOR chunk swizzle on LDS tiles (stage fetches global chunk lc^((lr>>1)&3);
// reads un-swizzle) -> 8-way bank conflicts become free 2-way. modw_k batched
// over b (512 blocks, weight row kept in registers).

#define CIN   512
#define COUT  512
#define KDIM  4608        // 9 * 512
#define HWPIX 4096

typedef __attribute__((ext_vector_type(8))) __bf16 bf16x8;
typedef __attribute__((ext_vector_type(4))) float  f32x4;

__device__ __forceinline__ unsigned short f2bf(float f){
  union { float f; unsigned int u; } v; v.f = f;
  unsigned int u = v.u;
  u += 0x7fffu + ((u >> 16) & 1u);     // round-to-nearest-even
  return (unsigned short)(u >> 16);
}

#define GLDS16(g, l) __builtin_amdgcn_global_load_lds(                      \
    (const __attribute__((address_space(1))) unsigned int*)(g),             \
    (__attribute__((address_space(3))) unsigned int*)(l), 16, 0, 0)

// ---------------- styles: s[b][c] = dot(w[b], affine_w[c]) + ab[c] + 1 ----
__global__ void style_k(const float* __restrict__ w, const float* __restrict__ aw,
                        const float* __restrict__ ab, float* __restrict__ styles){
  int wid = threadIdx.x >> 6, lane = threadIdx.x & 63;
  int gid = blockIdx.x * 4 + wid;           // 0..4095 = b*512 + c
  int b = gid >> 9, c = gid & 511;
  const float* wb = w + b * 512;
  const float* ar = aw + c * 512;
  float sum = 0.f;
  for (int j = lane; j < 512; j += 64) sum += wb[j] * ar[j];
  for (int off = 32; off; off >>= 1) sum += __shfl_down(sum, off, 64);
  if (lane == 0) styles[gid] = sum + ab[c] + 1.0f;
}

// ------------- modulate + demodulate -> bf16 wmod[b][o][tap*512+cin] ------
// One block per o; loops all 8 batches with the weight row cached in registers.
__global__ void modw_k(const float* __restrict__ weight, const float* __restrict__ styles,
                       unsigned short* __restrict__ wmod){
  int o = blockIdx.x;                  // 0..511
  int t = threadIdx.x;
  const float* wrow = weight + (size_t)o * KDIM;   // weight[0][o][i][ky][kx]
  float wv[18];
#pragma unroll
  for (int it = 0; it < 18; ++it) wv[it] = wrow[it * 256 + t];
  __shared__ unsigned short sw[9 * 520];           // tap stride 520 (pad vs 512)
  __shared__ float red[4];
  int wid = t >> 6, lane = t & 63;
  for (int b = 0; b < 8; ++b){
    const float* st = styles + b * 512;
    float vals[18];
    float part = 0.f;
#pragma unroll
    for (int it = 0; it < 18; ++it){
      int idx = it * 256 + t;
      int i = idx / 9;
      float v = wv[it] * st[i];
      vals[it] = v;
      part += v * v;
    }
    for (int off = 32; off; off >>= 1) part += __shfl_down(part, off, 64);
    if (lane == 0) red[wid] = part;
    __syncthreads();
    float d = rsqrtf(red[0] + red[1] + red[2] + red[3] + 1e-8f);
#pragma unroll
    for (int it = 0; it < 18; ++it){
      int idx = it * 256 + t;
      int i = idx / 9;
      int tap = idx - i * 9;
      sw[tap * 520 + i] = f2bf(vals[it] * d);
    }
    __syncthreads();
    unsigned int* orow32 = (unsigned int*)(wmod + ((size_t)(b * 512 + o)) * KDIM);
#pragma unroll
    for (int it = 0; it < 9; ++it){     // 2304 dwords, fully coalesced
      int u = it * 256 + t;
      int e = u * 2;
      int tap2 = e >> 9, i2 = e & 511;
      orow32[u] = *(const unsigned int*)&sw[tap2 * 520 + i2];
    }
    __syncthreads();                    // sw/red reused next b
  }
}

// ----- transpose+pad: x[b][c][h][w] fp32 -> xpad[b][h+1][w+1][c] bf16 -----
__global__ void xpose_k(const float* __restrict__ x, unsigned short* __restrict__ xpad){
  int h = blockIdx.x, cg = blockIdx.y, b = blockIdx.z;
  int c0 = cg * 64;
  __shared__ unsigned short lds[64][66];   // [w][c]: writes 2-way (free), reads clean
  int t = threadIdx.x;
  const float* xb = x + (((size_t)(b * 512 + c0)) * 64 + h) * 64;
#pragma unroll
  for (int it = 0; it < 16; ++it){
    int idx = it * 256 + t;
    int cl = idx >> 6, wl = idx & 63;     // cl wave-uniform, wl = lane
    lds[wl][cl] = f2bf(xb[(size_t)cl * 4096 + wl]);
  }
  if (t < 64){
    int which = t >> 5;                   // 0: w=0, 1: w=65
    int ch2 = (t & 31) * 2;
    int wl = which ? 65 : 0;
    *(unsigned int*)&xpad[(((size_t)b * 66 + h + 1) * 66 + wl) * 512 + c0 + ch2] = 0u;
  }
  if (h == 0 || h == 63){                 // rows 0 / 65, all 66 w
    int row = (h == 0) ? 0 : 65;
    for (int u = t; u < 66 * 32; u += 256){
      int wl = u >> 5, ch2 = (u & 31) * 2;
      *(unsigned int*)&xpad[(((size_t)b * 66 + row) * 66 + wl) * 512 + c0 + ch2] = 0u;
    }
  }
  __syncthreads();
#pragma unroll
  for (int it = 0; it < 2; ++it){
    int idx = it * 256 + t;
    int wl = idx >> 3, ch = idx & 7;
    unsigned int u0 = *(const unsigned int*)&lds[wl][ch * 8 + 0];
    unsigned int u1 = *(const unsigned int*)&lds[wl][ch * 8 + 2];
    unsigned int u2 = *(const unsigned int*)&lds[wl][ch * 8 + 4];
    unsigned int u3 = *(const unsigned int*)&lds[wl][ch * 8 + 6];
    int off = ((b * 66 + h + 1) * 66 + (wl + 1)) * 512 + c0 + ch * 8;
    *(uint4*)&xpad[off] = make_uint4(u0, u1, u2, u3);
  }
}

// --------------------------- main conv GEMM ------------------------------
// grid 512 (b==XCD swizzle); 256x128 block tile, 4 waves of 128x64 (8x4 frags);
// BK=64, 2-barrier K-loop, 16x16x32 MFMA. LDS 48KB. XOR chunk swizzle.
__global__ __launch_bounds__(256, 2) void conv_gemm(
    const unsigned short* __restrict__ wmod, const unsigned short* __restrict__ xpad,
    const float* __restrict__ noise, const float* __restrict__ bias,
    float* __restrict__ out){
  __shared__ unsigned short As[2][256 * 32];   // [slice][m][k32]  16KB each
  __shared__ unsigned short Bs[2][128 * 32];   // [slice][n][k32]   8KB each
  // decode: per XCD one batch (b = xcd), both m-tiles, all 32 n-tiles.
  int g = blockIdx.x;
  int xcd = g & 7, sl = g >> 3;                // sl 0..63
  int b = xcd, mt = sl >> 5, nt = sl & 31;
  int m0 = mt * 256, n0 = nt * 128;
  int h0 = nt * 2;                             // 2 image rows per n-tile
  int tid = threadIdx.x, wid = tid >> 6, lane = tid & 63;
  int wm = wid >> 1, wn = wid & 1;             // wave tile: rows wm*128, cols wn*64
  int lr = lane >> 2;                          // row within 16-row staging group
  int lc = lane & 3;                           // 16B chunk within 64B row
  int sc = lc ^ ((lr >> 1) & 3);               // swizzled global chunk to fetch

  const unsigned short* wbase = wmod + ((size_t)(b * 512 + m0)) * KDIM;
  int aoffG[4];
#pragma unroll
  for (int i = 0; i < 4; ++i)
    aoffG[i] = ((wid * 64 + i * 16 + lr)) * KDIM + sc * 8;   // A rows wid*64..+63

  const unsigned short* xb = xpad + (size_t)b * 66 * 66 * 512;
  int boffG[2];
#pragma unroll
  for (int i = 0; i < 2; ++i){
    int p = wid * 32 + i * 16 + lr;                          // B rows wid*32..+31
    boffG[i] = ((h0 + (p >> 6) + 1) * 66 + ((p & 63) + 1)) * 512 + sc * 8;
  }
  int albase[4], blbase[2];
#pragma unroll
  for (int i = 0; i < 4; ++i) albase[i] = (wid * 64 + i * 16) * 32;  // wave-uniform
#pragma unroll
  for (int i = 0; i < 2; ++i) blbase[i] = (wid * 32 + i * 16) * 32;

  int fm = lane & 15;
  int cidx = lane >> 4;                        // k-chunk wanted (8 elems each)
  int rk = cidx ^ ((fm >> 1) & 3);             // un-swizzle: LDS chunk to read
  int apo[8], bpo[4];
#pragma unroll
  for (int i = 0; i < 8; ++i) apo[i] = (wm * 128 + i * 16 + fm) * 32 + rk * 8;
#pragma unroll
  for (int j = 0; j < 4; ++j) bpo[j] = (wn * 64 + j * 16 + fm) * 32 + rk * 8;

  f32x4 acc[8][4];
#pragma unroll
  for (int i = 0; i < 8; ++i)
#pragma unroll
    for (int j = 0; j < 4; ++j) acc[i][j] = (f32x4){0.f, 0.f, 0.f, 0.f};

  for (int ks = 0; ks < 72; ++ks){
    int tap = ks >> 3;                      // 64 | 512: one tap per BK=64 step
    int c0  = (ks & 7) << 6;
    int k0  = (tap << 9) + c0;              // == ks*64
    int dy3 = tap / 3;
    int bshift = (((dy3 - 1) * 66 + (tap - dy3 * 3 - 1)) << 9) + c0;
    __syncthreads();                        // prior iter's ds_reads retired
#pragma unroll
    for (int i = 0; i < 4; ++i){
      GLDS16(wbase + aoffG[i] + k0,      &As[0][albase[i]]);
      GLDS16(wbase + aoffG[i] + k0 + 32, &As[1][albase[i]]);
    }
#pragma unroll
    for (int i = 0; i < 2; ++i){
      GLDS16(xb + boffG[i] + bshift,      &Bs[0][blbase[i]]);
      GLDS16(xb + boffG[i] + bshift + 32, &Bs[1][blbase[i]]);
    }
    __syncthreads();                        // drains vmcnt(0): staged data visible
#pragma unroll
    for (int s = 0; s < 2; ++s){
      bf16x8 af[8], bfr[4];
#pragma unroll
      for (int i = 0; i < 8; ++i) af[i]  = *(const bf16x8*)&As[s][apo[i]];
#pragma unroll
      for (int j = 0; j < 4; ++j) bfr[j] = *(const bf16x8*)&Bs[s][bpo[j]];
#pragma unroll
      for (int i = 0; i < 8; ++i)
#pragma unroll
        for (int j = 0; j < 4; ++j)
          acc[i][j] = __builtin_amdgcn_mfma_f32_16x16x32_bf16(af[i], bfr[j], acc[i][j], 0, 0, 0);
    }
  }

  // epilogue: + noise + bias, leaky relu 0.2. C/D map: row=(lane>>4)*4+reg, col=lane&15
  int quad = lane >> 4;
#pragma unroll
  for (int i = 0; i < 8; ++i){
    int o_base = m0 + wm * 128 + i * 16 + quad * 4;
#pragma unroll
    for (int j = 0; j < 4; ++j){
      int n = n0 + wn * 64 + j * 16 + fm;
#pragma unroll
      for (int r = 0; r < 4; ++r){
        int o = o_base + r;
        size_t idx = ((size_t)(b * 512 + o)) * HWPIX + n;
        float v = acc[i][j][r] + noise[idx] + bias[o];
        out[idx] = (v >= 0.f) ? v : 0.2f * v;
      }
    }
  }
}

extern "C" void kernel_launch(void* const* d_in, const int* in_sizes, int n_in,
                              void* d_out, int out_size, void* d_ws, size_t ws_size,
                              hipStream_t stream) {
  const float* x        = (const float*)d_in[0];
  const float* w        = (const float*)d_in[1];
  const float* noise    = (const float*)d_in[2];
  const float* weight   = (const float*)d_in[3];
  const float* affine_w = (const float*)d_in[4];
  const float* affine_b = (const float*)d_in[5];
  const float* bias     = (const float*)d_in[6];
  float* out = (float*)d_out;

  // workspace: styles 16KB | wmod 37,748,736B | xpad 35,684,352B  (~73.5 MB)
  float* styles = (float*)d_ws;
  unsigned short* wmod = (unsigned short*)((char*)d_ws + 16384);
  unsigned short* xpad = (unsigned short*)((char*)d_ws + 16384 + 37748736ull);

  style_k<<<dim3(1024), 256, 0, stream>>>(w, affine_w, affine_b, styles);
  modw_k <<<dim3(512), 256, 0, stream>>>(weight, styles, wmod);
  xpose_k<<<dim3(64, 8, 8), 256, 0, stream>>>(x, xpad);
  conv_gemm<<<dim3(512), 256, 0, stream>>>(wmod, xpad, noise, bias, out);
}